// Round 12
// baseline (310.084 us; speedup 1.0000x reference)
//
#include <hip/hip_runtime.h>
#include <hip/hip_bf16.h>

// CapsuleLayer dynamic routing, MI355X.
// B=32,N=2048,D=32 inputs; C=64,V=32 output caps; 3 routing rounds.
// u_hat (bf16 [n][b][p], 256MB ws) via MFMA; 3 fused routing passes using
// agreement linearity (b_logits = u_hat.(v1+v2+...)).
// Round 12: r11 (both streams dense, 305us) + two fixes:
// (1) precise vmcnt: r11's uniform vmcnt(4) counted the flush STORES ->
//     forced store-retire stall every other phase. Now vmcnt(6) post-flush
//     (skip 4 stores in queue), vmcnt(2) steady, vmcnt(0) last phase only.
// (2) occupancy: 2KB W chunks (32 phases) -> LDS 34KB -> 4 blocks/CU
//     (16 waves, was 3/12) to hide the per-wave wait points.

#define B_ 32
#define N_ 2048
#define D_ 32
#define C_ 64
#define V_ 32

typedef __attribute__((ext_vector_type(4))) float f32x4;
typedef __attribute__((ext_vector_type(4))) int i32x4;
typedef __attribute__((ext_vector_type(2))) int i32x2;
typedef __bf16 bf16x8 __attribute__((ext_vector_type(8)));

__device__ __forceinline__ unsigned f2bf1(float f) {
  unsigned u = __builtin_bit_cast(unsigned, f);
  return (u + 0x7FFFu + ((u >> 16) & 1u)) >> 16;  // RNE
}
__device__ __forceinline__ float bf2f(unsigned h) {
  unsigned u = h << 16;
  return __builtin_bit_cast(float, u);
}

__device__ __forceinline__ bf16x8 cvt_frag(f32x4 lo, f32x4 hi) {
  i32x4 r;
  r[0] = f2bf1(lo[0]) | (f2bf1(lo[1]) << 16);
  r[1] = f2bf1(lo[2]) | (f2bf1(lo[3]) << 16);
  r[2] = f2bf1(hi[0]) | (f2bf1(hi[1]) << 16);
  r[3] = f2bf1(hi[2]) | (f2bf1(hi[3]) << 16);
  return __builtin_bit_cast(bf16x8, r);
}

__device__ __forceinline__ void gload16(const float* g, float* l) {
  __builtin_amdgcn_global_load_lds(
      (const __attribute__((address_space(1))) void*)g,
      (__attribute__((address_space(3))) void*)l, 16, 0, 0);
}

// u_hat[n][b][p], bf16. Block = one n, 4 waves; wave owns 512 p-rows.
// 32 phases x 16 rows (1 ptile): stage 2KB (2x gload16, 1KB dense each,
// src pre-swizzled) -> 2 MFMA -> 8B ds_writes into [32b][64p] tile ->
// every 4th phase flush as 4 dense stores (8 rows x 128B full lines each).
__global__ __launch_bounds__(256) void uhat_kernel(const float* __restrict__ x,
                                                   const float* __restrict__ W,
                                                   unsigned short* __restrict__ uh) {
  const int n = blockIdx.x;
  const int wave = threadIdx.x >> 6;
  const int l = threadIdx.x & 63;
  const int l16 = l & 15, kg = l >> 4;    // fragment roles
  const int lrow = l >> 3, lcol = l & 7;  // staging roles (8 rows x 8 slots)

  __shared__ float wlds[4][2][512];            // 16KB: W chunks, dbuf
  __shared__ unsigned short olds[4][32 * 72];  // 18KB: out tiles
  float* wbuf0 = &wlds[wave][0][0];
  float* wbuf1 = &wlds[wave][1][0];
  unsigned short* obuf = &olds[wave][0];

  // B-operand = x: lane l16 = col b (+16 per bt), k = kg*8..+7
  bf16x8 xb[2];
#pragma unroll
  for (int bt = 0; bt < 2; ++bt) {
    const float* xp = x + (((size_t)(bt * 16 + l16)) * N_ + n) * D_ + kg * 8;
    xb[bt] = cvt_frag(*(const f32x4*)xp, *(const f32x4*)(xp + 4));
  }
  __builtin_amdgcn_sched_barrier(0);  // x loads consumed above this point

  const f32x4 zero = {0.f, 0.f, 0.f, 0.f};
  // dense staging source with inverse swizzle (r9-verified, per-8-row group)
  const int src_off_f = lrow * 32 + (((lcol * 16) ^ (lrow << 4)) >> 2);
  const float* wsrc = W + (size_t)n * 65536 + (size_t)wave * 16384 + src_off_f;
  unsigned short* ubase = uh + (size_t)n * 65536 + wave * 512;  // + b*2048 + p
  const unsigned char* rb0 = (const unsigned char*)wbuf0;
  const unsigned char* rb1 = (const unsigned char*)wbuf1;
  const int a_base = (kg * 32) ^ ((l16 & 7) << 4);  // swizzled frag col
  const int a0 = l16 * 128 + a_base;                // row l16 of 16-row chunk

  // prologue: stage phase 0
  gload16(wsrc, wbuf0);
  gload16(wsrc + 256, wbuf0 + 256);

#pragma unroll
  for (int ph = 0; ph < 32; ++ph) {
    if (ph < 31) {
      const float* ws = wsrc + (size_t)(ph + 1) * 512;
      float* dbuf = ((ph + 1) & 1) ? wbuf1 : wbuf0;
      gload16(ws, dbuf);
      gload16(ws + 256, dbuf + 256);
    }
    // wait for THIS phase's 2 loads; queue after issue:
    //  ph%4==0 (flush at ph-1): [L_ph(2), S(4), L_ph+1(2)] -> vmcnt(6)
    //  else steady:             [L_ph(2), L_ph+1(2)]       -> vmcnt(2)
    //  ph==31: nothing issued   [L_31(2)]                  -> vmcnt(0)
    if (ph == 31) {
      asm volatile("s_waitcnt vmcnt(0)" ::: "memory");
    } else if ((ph & 3) == 0 && ph != 0) {
      asm volatile("s_waitcnt vmcnt(6)" ::: "memory");
    } else {
      asm volatile("s_waitcnt vmcnt(2)" ::: "memory");
    }
    __builtin_amdgcn_sched_barrier(0);
    const unsigned char* rb = (ph & 1) ? rb1 : rb0;
    {
      f32x4 lo = *(const f32x4*)(rb + a0);
      f32x4 hi = *(const f32x4*)(rb + (a0 ^ 16));
      bf16x8 wfrag = cvt_frag(lo, hi);
#pragma unroll
      for (int bt = 0; bt < 2; ++bt) {
        f32x4 acc = __builtin_amdgcn_mfma_f32_16x16x32_bf16(wfrag, xb[bt], zero, 0, 0, 0);
        i32x2 dv;
        dv[0] = (int)(f2bf1(acc[0]) | (f2bf1(acc[1]) << 16));
        dv[1] = (int)(f2bf1(acc[2]) | (f2bf1(acc[3]) << 16));
        // out tile: row b = bt*16+l16 (stride 72), p_local = (ph&3)*16 + kg*4
        *(i32x2*)(obuf + (bt * 16 + l16) * 72 + (ph & 3) * 16 + kg * 4) = dv;
      }
    }
    if ((ph & 3) == 3) {
      // all 4 phases' tile writes visible before cross-lane gather
      asm volatile("s_waitcnt lgkmcnt(0)" ::: "memory");
      __builtin_amdgcn_sched_barrier(0);
      const int pbase = (ph >> 2) * 64;  // 0..448
#pragma unroll
      for (int i = 0; i < 4; ++i) {
        const int b = i * 8 + (l >> 3);
        const unsigned short* s = obuf + b * 72 + (l & 7) * 8;
        i32x4 v = *(const i32x4*)s;
        *(i32x4*)(ubase + (size_t)b * 2048 + pbase + (l & 7) * 8) = v;
      }
      __builtin_amdgcn_sched_barrier(0);
      // gather reads retire before the store consumes them (reg dep), so
      // next group's ds_writes are WAR-safe without an extra fence
    }
  }
}

// Routing pass: s[b,c,v] = sum_n softmax_c(u_hat[b,n,:,:].vsum[b,:,:])[c] * u_hat[b,n,c,v]
// wave lane l == c. Block = 4 waves x 16 n, same b. Partials (no atomics) to ws.
template <int ROUND>
__global__ __launch_bounds__(256) void routing_kernel(const unsigned short* __restrict__ uh,
                                                      const float* __restrict__ vsum,
                                                      float* __restrict__ part) {
  const int b = blockIdx.x >> 5;  // 32 chunks per b
  const int chunk = blockIdx.x & 31;
  const int wave = threadIdx.x >> 6;
  const int l = threadIdx.x & 63;  // = c

  float vs[32];
  if (ROUND >= 2) {
    const f32x4* vp = (const f32x4*)(vsum + ((size_t)b * 64 + l) * 32);
#pragma unroll
    for (int i = 0; i < 8; ++i) {
      f32x4 t = vp[i];
      vs[4 * i] = t[0]; vs[4 * i + 1] = t[1]; vs[4 * i + 2] = t[2]; vs[4 * i + 3] = t[3];
    }
  }
  float sacc[32];
#pragma unroll
  for (int v = 0; v < 32; ++v) sacc[v] = 0.f;

  const int n0 = chunk * 64 + wave * 16;
  for (int ni = 0; ni < 16; ++ni) {
    const int n = n0 + ni;
    const i32x4* up = (const i32x4*)(uh + ((size_t)n * 32 + b) * 2048 + l * 32);
    i32x4 qs0 = up[0], qs1 = up[1], qs2 = up[2], qs3 = up[3];
    float u[32];
#pragma unroll
    for (int i = 0; i < 4; ++i) {
      unsigned v0 = (unsigned)qs0[i], v1 = (unsigned)qs1[i], v2 = (unsigned)qs2[i], v3 = (unsigned)qs3[i];
      u[0 + 2 * i] = bf2f(v0 & 0xffffu);  u[0 + 2 * i + 1] = bf2f(v0 >> 16);
      u[8 + 2 * i] = bf2f(v1 & 0xffffu);  u[8 + 2 * i + 1] = bf2f(v1 >> 16);
      u[16 + 2 * i] = bf2f(v2 & 0xffffu); u[16 + 2 * i + 1] = bf2f(v2 >> 16);
      u[24 + 2 * i] = bf2f(v3 & 0xffffu); u[24 + 2 * i + 1] = bf2f(v3 >> 16);
    }
    float r;
    if (ROUND >= 2) {
      float br = 0.f;
#pragma unroll
      for (int v = 0; v < 32; ++v) br = fmaf(u[v], vs[v], br);
      float m = br;
#pragma unroll
      for (int off = 32; off; off >>= 1) m = fmaxf(m, __shfl_xor(m, off, 64));
      float e = __expf(br - m);
      float den = e;
#pragma unroll
      for (int off = 32; off; off >>= 1) den += __shfl_xor(den, off, 64);
      r = e / den;
    } else {
      r = 1.0f / 64.0f;  // softmax of zeros
    }
#pragma unroll
    for (int v = 0; v < 32; ++v) sacc[v] = fmaf(r, u[v], sacc[v]);
  }

  __shared__ float red[4][64][33];  // +1 pad: conflict-free
#pragma unroll
  for (int v = 0; v < 32; ++v) red[wave][l][v] = sacc[v];
  __syncthreads();
  const int t = threadIdx.x;
  f32x4 o0, o1;
#pragma unroll
  for (int i = 0; i < 4; ++i) {
    const int e0 = t * 8 + i, e1 = t * 8 + 4 + i;
    o0[i] = red[0][e0 >> 5][e0 & 31] + red[1][e0 >> 5][e0 & 31] +
            red[2][e0 >> 5][e0 & 31] + red[3][e0 >> 5][e0 & 31];
    o1[i] = red[0][e1 >> 5][e1 & 31] + red[1][e1 >> 5][e1 & 31] +
            red[2][e1 >> 5][e1 & 31] + red[3][e1 >> 5][e1 & 31];
  }
  float* pp = part + ((size_t)blockIdx.x) * 2048 + t * 8;
  *(f32x4*)pp = o0;
  *(f32x4*)(pp + 4) = o1;
}

// Reduce partials -> s, squash -> v. Writes v to out; maintains vsum for agreement.
template <int ROUND>
__global__ __launch_bounds__(256) void squash_kernel(const float* __restrict__ part,
                                                     float* __restrict__ vsum,
                                                     float* __restrict__ out) {
  const int t = blockIdx.x * 256 + threadIdx.x;  // 0..65535 = b*2048 + c*32 + v
  const int b = t >> 11;
  const int e = t & 2047;
  float sv = 0.f;
#pragma unroll
  for (int k = 0; k < 32; ++k) sv += part[((size_t)(b * 32 + k)) * 2048 + e];
  float sq = sv * sv;
#pragma unroll
  for (int off = 16; off; off >>= 1) sq += __shfl_xor(sq, off, 64);  // sum over v (32-lane groups)
  float scale = (sq / (1.f + sq)) * rsqrtf(sq + 1e-9f);
  float val = sv * scale;
  out[t] = val;
  if (ROUND == 1) vsum[t] = val;
  else if (ROUND == 2) vsum[t] += val;
}

extern "C" void kernel_launch(void* const* d_in, const int* in_sizes, int n_in,
                              void* d_out, int out_size, void* d_ws, size_t ws_size,
                              hipStream_t stream) {
  const float* x = (const float*)d_in[0];  // [B,N,D]
  const float* W = (const float*)d_in[1];  // [1,N,C,V,D]
  float* out = (float*)d_out;              // [B,1,C,V,1] = 65536 fp32

  const size_t UH_BYTES = (size_t)B_ * N_ * C_ * V_ * 2;  // 268435456
  const size_t PART_BYTES = (size_t)B_ * 32 * 2048 * 4;   // 8388608
  const size_t VSUM_BYTES = (size_t)B_ * C_ * V_ * 4;     // 262144
  if (ws_size < UH_BYTES + PART_BYTES + VSUM_BYTES) return;  // can't run

  unsigned short* uh = (unsigned short*)d_ws;
  float* part = (float*)((char*)d_ws + UH_BYTES);
  float* vsum = (float*)((char*)d_ws + UH_BYTES + PART_BYTES);

  uhat_kernel<<<N_, 256, 0, stream>>>(x, W, uh);
  routing_kernel<1><<<B_ * 32, 256, 0, stream>>>(uh, vsum, part);
  squash_kernel<1><<<256, 256, 0, stream>>>(part, vsum, out);
  routing_kernel<2><<<B_ * 32, 256, 0, stream>>>(uh, vsum, part);
  squash_kernel<2><<<256, 256, 0, stream>>>(part, vsum, out);
  routing_kernel<3><<<B_ * 32, 256, 0, stream>>>(uh, vsum, part);
  squash_kernel<3><<<256, 256, 0, stream>>>(part, vsum, out);
}

// Round 13
// 306.668 us; speedup vs baseline: 1.0111x; 1.0111x over previous
//
#include <hip/hip_runtime.h>
#include <hip/hip_bf16.h>

// CapsuleLayer dynamic routing, MI355X.
// B=32,N=2048,D=32 inputs; C=64,V=32 output caps; 3 routing rounds.
// u_hat (bf16 [n][b][p], 256MB ws) via MFMA; 3 fused routing passes using
// agreement linearity (b_logits = u_hat.(v1+v2+...)).
// Round 13: kill the per-phase vmcnt rendezvous. copy_diag (identical traffic,
// zero waits) runs 5.2 TB/s app vs uhat's 3.9; every gload_lds variant must
// synchronize consumption with coarse vmcnt each phase. Now: lane loads 32B
// contiguous W (dense-paired lines, register dest), and the MFMA fragment is
// exactly one other lane's 32B -> redistribute with 8 ds_bpermute_b32
// (constant index). No staging LDS, no vmcnt/fences on the read side;
// compiler pipelines the loads freely (2-deep register ring on top).
// Store path unchanged from r11/r12 (dense out-tile flush every 4 phases).

#define B_ 32
#define N_ 2048
#define D_ 32
#define C_ 64
#define V_ 32

typedef __attribute__((ext_vector_type(4))) float f32x4;
typedef __attribute__((ext_vector_type(4))) int i32x4;
typedef __attribute__((ext_vector_type(2))) int i32x2;
typedef __bf16 bf16x8 __attribute__((ext_vector_type(8)));

__device__ __forceinline__ unsigned f2bf1(float f) {
  unsigned u = __builtin_bit_cast(unsigned, f);
  return (u + 0x7FFFu + ((u >> 16) & 1u)) >> 16;  // RNE
}
__device__ __forceinline__ float bf2f(unsigned h) {
  unsigned u = h << 16;
  return __builtin_bit_cast(float, u);
}

__device__ __forceinline__ bf16x8 cvt_frag(f32x4 lo, f32x4 hi) {
  i32x4 r;
  r[0] = f2bf1(lo[0]) | (f2bf1(lo[1]) << 16);
  r[1] = f2bf1(lo[2]) | (f2bf1(lo[3]) << 16);
  r[2] = f2bf1(hi[0]) | (f2bf1(hi[1]) << 16);
  r[3] = f2bf1(hi[2]) | (f2bf1(hi[3]) << 16);
  return __builtin_bit_cast(bf16x8, r);
}

// u_hat[n][b][p], bf16. Block = one n, 4 waves; wave owns 512 p-rows.
// 32 phases x 16 rows: lane loads its 32B of the 2KB chunk (register dest,
// no waits) -> 8 ds_bpermute gather the fragment (src lane = l16*4+kg) ->
// cvt -> 2 MFMA -> 8B ds_writes into [32b][64p] tile (stride 72) ->
// every 4th phase flush as 4 dense stores (8 rows x 128B full lines each).
__global__ __launch_bounds__(256) void uhat_kernel(const float* __restrict__ x,
                                                   const float* __restrict__ W,
                                                   unsigned short* __restrict__ uh) {
  const int n = blockIdx.x;
  const int wave = threadIdx.x >> 6;
  const int l = threadIdx.x & 63;
  const int l16 = l & 15, kg = l >> 4;  // fragment roles

  __shared__ unsigned short olds[4][32 * 72];  // 18KB: out tiles
  unsigned short* obuf = &olds[wave][0];

  // B-operand = x: lane l16 = col b (+16 per bt), k = kg*8..+7
  bf16x8 xb[2];
#pragma unroll
  for (int bt = 0; bt < 2; ++bt) {
    const float* xp = x + (((size_t)(bt * 16 + l16)) * N_ + n) * D_ + kg * 8;
    xb[bt] = cvt_frag(*(const f32x4*)xp, *(const f32x4*)(xp + 4));
  }

  const f32x4 zero = {0.f, 0.f, 0.f, 0.f};
  // W loads: lane owns 32B of each 2KB phase chunk (floats [l*8, l*8+8))
  const float* wsrc = W + (size_t)n * 65536 + (size_t)wave * 16384 + l * 8;
  unsigned short* ubase = uh + (size_t)n * 65536 + wave * 512;  // + b*2048 + p
  // fragment source lane: s = l16*4 + kg; bpermute index in bytes = s*4
  const int bp = ((((l & 15) << 2) | (l >> 4)) << 2);

  // 2-deep register ring (compile-time indices via full unroll)
  f32x4 wa[2], wb[2];
  wa[0] = *(const f32x4*)(wsrc);
  wb[0] = *(const f32x4*)(wsrc + 4);
  wa[1] = *(const f32x4*)(wsrc + 512);
  wb[1] = *(const f32x4*)(wsrc + 516);

#pragma unroll
  for (int ph = 0; ph < 32; ++ph) {
    f32x4 ca = wa[ph & 1], cb = wb[ph & 1];
    if (ph < 30) {
      const float* wp = wsrc + (size_t)(ph + 2) * 512;
      wa[ph & 1] = *(const f32x4*)(wp);
      wb[ph & 1] = *(const f32x4*)(wp + 4);
    }
    // redistribute: lane gets all 8 floats of lane s = l16*4+kg
    i32x4 ia = __builtin_bit_cast(i32x4, ca), ib = __builtin_bit_cast(i32x4, cb);
    i32x4 oa, ob;
#pragma unroll
    for (int j = 0; j < 4; ++j) {
      oa[j] = __builtin_amdgcn_ds_bpermute(bp, ia[j]);
      ob[j] = __builtin_amdgcn_ds_bpermute(bp, ib[j]);
    }
    bf16x8 wfrag = cvt_frag(__builtin_bit_cast(f32x4, oa), __builtin_bit_cast(f32x4, ob));
#pragma unroll
    for (int bt = 0; bt < 2; ++bt) {
      f32x4 acc = __builtin_amdgcn_mfma_f32_16x16x32_bf16(wfrag, xb[bt], zero, 0, 0, 0);
      i32x2 dv;
      dv[0] = (int)(f2bf1(acc[0]) | (f2bf1(acc[1]) << 16));
      dv[1] = (int)(f2bf1(acc[2]) | (f2bf1(acc[3]) << 16));
      // out tile: row b = bt*16+l16 (stride 72), p_local = (ph&3)*16 + kg*4
      *(i32x2*)(obuf + (bt * 16 + l16) * 72 + (ph & 3) * 16 + kg * 4) = dv;
    }
    if ((ph & 3) == 3) {
      // all 4 phases' tile writes visible before cross-lane gather
      asm volatile("s_waitcnt lgkmcnt(0)" ::: "memory");
      __builtin_amdgcn_sched_barrier(0);
      const int pbase = (ph >> 2) * 64;  // 0..448
#pragma unroll
      for (int i = 0; i < 4; ++i) {
        const int b = i * 8 + (l >> 3);
        const unsigned short* s = obuf + b * 72 + (l & 7) * 8;
        i32x4 v = *(const i32x4*)s;
        *(i32x4*)(ubase + (size_t)b * 2048 + pbase + (l & 7) * 8) = v;
      }
      __builtin_amdgcn_sched_barrier(0);
      // gather ds_reads precede next group's ds_writes in the in-order LDS
      // pipe (same wave, aliasing addresses) -> WAR-safe
    }
  }
}

// Routing pass: s[b,c,v] = sum_n softmax_c(u_hat[b,n,:,:].vsum[b,:,:])[c] * u_hat[b,n,c,v]
// wave lane l == c. Block = 4 waves x 16 n, same b. Partials (no atomics) to ws.
template <int ROUND>
__global__ __launch_bounds__(256) void routing_kernel(const unsigned short* __restrict__ uh,
                                                      const float* __restrict__ vsum,
                                                      float* __restrict__ part) {
  const int b = blockIdx.x >> 5;  // 32 chunks per b
  const int chunk = blockIdx.x & 31;
  const int wave = threadIdx.x >> 6;
  const int l = threadIdx.x & 63;  // = c

  float vs[32];
  if (ROUND >= 2) {
    const f32x4* vp = (const f32x4*)(vsum + ((size_t)b * 64 + l) * 32);
#pragma unroll
    for (int i = 0; i < 8; ++i) {
      f32x4 t = vp[i];
      vs[4 * i] = t[0]; vs[4 * i + 1] = t[1]; vs[4 * i + 2] = t[2]; vs[4 * i + 3] = t[3];
    }
  }
  float sacc[32];
#pragma unroll
  for (int v = 0; v < 32; ++v) sacc[v] = 0.f;

  const int n0 = chunk * 64 + wave * 16;
  for (int ni = 0; ni < 16; ++ni) {
    const int n = n0 + ni;
    const i32x4* up = (const i32x4*)(uh + ((size_t)n * 32 + b) * 2048 + l * 32);
    i32x4 qs0 = up[0], qs1 = up[1], qs2 = up[2], qs3 = up[3];
    float u[32];
#pragma unroll
    for (int i = 0; i < 4; ++i) {
      unsigned v0 = (unsigned)qs0[i], v1 = (unsigned)qs1[i], v2 = (unsigned)qs2[i], v3 = (unsigned)qs3[i];
      u[0 + 2 * i] = bf2f(v0 & 0xffffu);  u[0 + 2 * i + 1] = bf2f(v0 >> 16);
      u[8 + 2 * i] = bf2f(v1 & 0xffffu);  u[8 + 2 * i + 1] = bf2f(v1 >> 16);
      u[16 + 2 * i] = bf2f(v2 & 0xffffu); u[16 + 2 * i + 1] = bf2f(v2 >> 16);
      u[24 + 2 * i] = bf2f(v3 & 0xffffu); u[24 + 2 * i + 1] = bf2f(v3 >> 16);
    }
    float r;
    if (ROUND >= 2) {
      float br = 0.f;
#pragma unroll
      for (int v = 0; v < 32; ++v) br = fmaf(u[v], vs[v], br);
      float m = br;
#pragma unroll
      for (int off = 32; off; off >>= 1) m = fmaxf(m, __shfl_xor(m, off, 64));
      float e = __expf(br - m);
      float den = e;
#pragma unroll
      for (int off = 32; off; off >>= 1) den += __shfl_xor(den, off, 64);
      r = e / den;
    } else {
      r = 1.0f / 64.0f;  // softmax of zeros
    }
#pragma unroll
    for (int v = 0; v < 32; ++v) sacc[v] = fmaf(r, u[v], sacc[v]);
  }

  __shared__ float red[4][64][33];  // +1 pad: conflict-free
#pragma unroll
  for (int v = 0; v < 32; ++v) red[wave][l][v] = sacc[v];
  __syncthreads();
  const int t = threadIdx.x;
  f32x4 o0, o1;
#pragma unroll
  for (int i = 0; i < 4; ++i) {
    const int e0 = t * 8 + i, e1 = t * 8 + 4 + i;
    o0[i] = red[0][e0 >> 5][e0 & 31] + red[1][e0 >> 5][e0 & 31] +
            red[2][e0 >> 5][e0 & 31] + red[3][e0 >> 5][e0 & 31];
    o1[i] = red[0][e1 >> 5][e1 & 31] + red[1][e1 >> 5][e1 & 31] +
            red[2][e1 >> 5][e1 & 31] + red[3][e1 >> 5][e1 & 31];
  }
  float* pp = part + ((size_t)blockIdx.x) * 2048 + t * 8;
  *(f32x4*)pp = o0;
  *(f32x4*)(pp + 4) = o1;
}

// Reduce partials -> s, squash -> v. Writes v to out; maintains vsum for agreement.
template <int ROUND>
__global__ __launch_bounds__(256) void squash_kernel(const float* __restrict__ part,
                                                     float* __restrict__ vsum,
                                                     float* __restrict__ out) {
  const int t = blockIdx.x * 256 + threadIdx.x;  // 0..65535 = b*2048 + c*32 + v
  const int b = t >> 11;
  const int e = t & 2047;
  float sv = 0.f;
#pragma unroll
  for (int k = 0; k < 32; ++k) sv += part[((size_t)(b * 32 + k)) * 2048 + e];
  float sq = sv * sv;
#pragma unroll
  for (int off = 16; off; off >>= 1) sq += __shfl_xor(sq, off, 64);  // sum over v (32-lane groups)
  float scale = (sq / (1.f + sq)) * rsqrtf(sq + 1e-9f);
  float val = sv * scale;
  out[t] = val;
  if (ROUND == 1) vsum[t] = val;
  else if (ROUND == 2) vsum[t] += val;
}

extern "C" void kernel_launch(void* const* d_in, const int* in_sizes, int n_in,
                              void* d_out, int out_size, void* d_ws, size_t ws_size,
                              hipStream_t stream) {
  const float* x = (const float*)d_in[0];  // [B,N,D]
  const float* W = (const float*)d_in[1];  // [1,N,C,V,D]
  float* out = (float*)d_out;              // [B,1,C,V,1] = 65536 fp32

  const size_t UH_BYTES = (size_t)B_ * N_ * C_ * V_ * 2;  // 268435456
  const size_t PART_BYTES = (size_t)B_ * 32 * 2048 * 4;   // 8388608
  const size_t VSUM_BYTES = (size_t)B_ * C_ * V_ * 4;     // 262144
  if (ws_size < UH_BYTES + PART_BYTES + VSUM_BYTES) return;  // can't run

  unsigned short* uh = (unsigned short*)d_ws;
  float* part = (float*)((char*)d_ws + UH_BYTES);
  float* vsum = (float*)((char*)d_ws + UH_BYTES + PART_BYTES);

  uhat_kernel<<<N_, 256, 0, stream>>>(x, W, uh);
  routing_kernel<1><<<B_ * 32, 256, 0, stream>>>(uh, vsum, part);
  squash_kernel<1><<<256, 256, 0, stream>>>(part, vsum, out);
  routing_kernel<2><<<B_ * 32, 256, 0, stream>>>(uh, vsum, part);
  squash_kernel<2><<<256, 256, 0, stream>>>(part, vsum, out);
  routing_kernel<3><<<B_ * 32, 256, 0, stream>>>(uh, vsum, part);
  squash_kernel<3><<<256, 256, 0, stream>>>(part, vsum, out);
}